// Round 9
// baseline (403.379 us; speedup 1.0000x reference)
//
#include <hip/hip_runtime.h>
#include <hip/hip_bf16.h>
#include <float.h>

#define F_DIM 64
#define H_DIM 128
#define LW2   104   // wt2 row stride (bf16) for K=96 [x[e0]|ppf|pad]: 208 B, 16B-aligned
#define LW1   72    // w1t row stride (bf16) for K=64 [x[e1]]: 144 B, 16B-aligned
#define QCH   2     // segments grabbed per queue atomic

typedef __attribute__((ext_vector_type(8))) short short8;   // 8 bf16 (mfma A/B frag)
typedef __attribute__((ext_vector_type(4))) float f32x4;    // mfma C/D frag

__device__ __forceinline__ unsigned short f2bf(float f) {
    __hip_bfloat16 h = __float2bfloat16(f);
    return __builtin_bit_cast(unsigned short, h);
}
__device__ __forceinline__ unsigned pk(float a, float b) {
    return (unsigned)f2bf(a) | ((unsigned)f2bf(b) << 16);
}

__device__ __forceinline__ float angle3(float ax, float ay, float az,
                                        float bx, float by, float bz) {
    float cx = ay*bz - az*by;
    float cy = az*bx - ax*bz;
    float cz = ax*by - ay*bx;
    float cn = sqrtf(cx*cx + cy*cy + cz*cz);
    float d  = ax*bx + ay*by + az*bz;
    return atan2f(cn, d);
}

// fused streaming pass: wt2 + w1t builds, xbf (x->bf16 mfma layout), node2slot scatter,
// per-NODE edge histogram with rank capture (atomic return is the free rank), pos tail,
// queue-counter zero. cnt_node must be zeroed (hipMemsetAsync) before this kernel.
__global__ __launch_bounds__(256)
void prep0(const float* __restrict__ W, unsigned short* __restrict__ wt2,
           unsigned short* __restrict__ w1t, const float* __restrict__ x,
           unsigned short* __restrict__ xbf, const int* __restrict__ idx,
           int* __restrict__ node2slot, const int* __restrict__ edge,
           int* __restrict__ cnt_node, unsigned short* __restrict__ rank16,
           const float* __restrict__ pos, float* __restrict__ out,
           int* __restrict__ qctr, int S, int E, int NF8) {
    const int T = gridDim.x * blockDim.x;
    const int gid = blockIdx.x * blockDim.x + threadIdx.x;
    if (gid == 0) *qctr = 0;
    for (int g = gid; g < NF8; g += T) {                  // x[N][64] f32 -> bf16, 8/thread
        const float4* s4 = (const float4*)x + (size_t)g * 2;
        float4 f0 = s4[0], f1 = s4[1];
        uint4 q;
        q.x = pk(f0.x, f0.y); q.y = pk(f0.z, f0.w);
        q.z = pk(f1.x, f1.y); q.w = pk(f1.z, f1.w);
        ((uint4*)xbf)[g] = q;
    }
    for (int g = gid; g < H_DIM * LW2; g += T) {          // W rows 64..131 -> [H][LW2]
        int h = g / LW2, k = g % LW2;
        float v = 0.f;
        if (k < F_DIM)          v = W[(F_DIM + k) * H_DIM + h];
        else if (k < F_DIM + 4) v = W[(2 * F_DIM + (k - F_DIM)) * H_DIM + h];
        wt2[g] = f2bf(v);
    }
    for (int g = gid; g < H_DIM * LW1; g += T) {          // W rows 0..63 -> [H][LW1]
        int h = g / LW1, k = g % LW1;
        w1t[g] = f2bf((k < F_DIM) ? W[k * H_DIM + h] : 0.f);
    }
    for (int g = gid; g < S; g += T) node2slot[idx[g]] = g;  // any winner = canonical slot
    for (int g = gid; g < E; g += T) {                       // per-node histogram + rank
        int e1 = edge[E + g];
        rank16[g] = (unsigned short)atomicAdd(&cnt_node[e1], 1);
    }
    for (int g = gid; g < 3 * S; g += T)                     // out tail = pos[idx]
        out[(size_t)S * H_DIM + g] = pos[(size_t)idx[g / 3] * 3 + (g % 3)];
}

// blocks [0,AB): per-slot range alloc (canonical slots carry their node's count) -> off.
// blocks [AB,AB+CB): cmat = b + x[idx]·W1 -> out
__global__ __launch_bounds__(256)
void alloc_cmat(const int* __restrict__ cnt_node, const int* __restrict__ node2slot,
                int* __restrict__ off, int* __restrict__ total,
                const unsigned short* __restrict__ xbf,
                const unsigned short* __restrict__ w1t, const float* __restrict__ bias,
                const int* __restrict__ idx, float* __restrict__ out, int S, int AB) {
    __shared__ int wsum[4];
    __shared__ int bb;
    __shared__ __align__(16) unsigned short a_lds[64 * LW1];
    const int tid = threadIdx.x;

    if ((int)blockIdx.x < AB) {
        int s = blockIdx.x * 256 + tid;
        int v = 0;
        if (s < S) {
            int node = idx[s];
            if (node2slot[node] == s) v = cnt_node[node];   // non-canonical dup slot -> 0
        }
        int lane = tid & 63, wv = tid >> 6;
        int sc = v;
        #pragma unroll
        for (int d = 1; d < 64; d <<= 1) {
            int t = __shfl_up(sc, d, 64);
            if (lane >= d) sc += t;
        }
        if (lane == 63) wsum[wv] = sc;
        __syncthreads();
        if (tid == 0) {
            int t = 0;
            #pragma unroll
            for (int i = 0; i < 4; ++i) { int w = wsum[i]; wsum[i] = t; t += w; }
            bb = atomicAdd(total, t);
        }
        __syncthreads();
        int excl = bb + wsum[wv] + sc - v;
        if (s < S) off[s] = excl;
        return;
    }

    // ---- cmat: 64 slots per block, A rows from xbf (already bf16) ----
    const int sbase = (blockIdx.x - AB) * 64;
    const int m = tid >> 2, p = tid & 3;
    {
        int s = sbase + m; if (s >= S) s = S - 1;
        int node = idx[s];
        const uint4* src = (const uint4*)(xbf + (size_t)node * F_DIM) + p * 2;
        uint4* dst = (uint4*)(a_lds + m * LW1 + p * 16);
        dst[0] = src[0]; dst[1] = src[1];
        if (p == 0) *(uint4*)(a_lds + m * LW1 + 64) = make_uint4(0, 0, 0, 0);
    }
    __syncthreads();
    const int wv = tid >> 6, lane = tid & 63, l15 = lane & 15, quad = lane >> 4;
    const int n0 = wv * 32 + l15, n1 = n0 + 16;
    f32x4 acc[4][2];
    #pragma unroll
    for (int i = 0; i < 4; ++i) {
        acc[i][0] = (f32x4){0.f, 0.f, 0.f, 0.f};
        acc[i][1] = (f32x4){0.f, 0.f, 0.f, 0.f};
    }
    #pragma unroll
    for (int ks = 0; ks < 2; ++ks) {
        const int ko = ks * 32 + quad * 8;
        short8 bf0 = *(const short8*)(w1t + (size_t)n0 * LW1 + ko);
        short8 bf1 = *(const short8*)(w1t + (size_t)n1 * LW1 + ko);
        #pragma unroll
        for (int mt = 0; mt < 4; ++mt) {
            short8 af = *(const short8*)(a_lds + (mt * 16 + l15) * LW1 + ko);
            acc[mt][0] = __builtin_amdgcn_mfma_f32_16x16x32_bf16(af, bf0, acc[mt][0], 0, 0, 0);
            acc[mt][1] = __builtin_amdgcn_mfma_f32_16x16x32_bf16(af, bf1, acc[mt][1], 0, 0, 0);
        }
    }
    const float b0 = bias[n0], b1 = bias[n1];
    #pragma unroll
    for (int mt = 0; mt < 4; ++mt) {
        #pragma unroll
        for (int r = 0; r < 4; ++r) {
            int s = sbase + mt * 16 + quad * 4 + r;     // C/D: row = quad*4 + reg
            if (s < S) {
                out[(size_t)s * H_DIM + n0] = acc[mt][0][r] + b0;
                out[(size_t)s * H_DIM + n1] = acc[mt][1][r] + b1;
            }
        }
    }
}

// ATOMIC-FREE placement: p = off[slot(e1)] + rank[e]; gathers + trig + one 16B record write.
__global__ void place_kernel(const int* __restrict__ edge, const float* __restrict__ pos,
                             const float* __restrict__ normal,
                             const int* __restrict__ node2slot,
                             const unsigned short* __restrict__ rank16,
                             const int* __restrict__ off, uint4* __restrict__ prec, int E) {
    int e = blockIdx.x * blockDim.x + threadIdx.x;
    if (e >= E) return;
    int e0 = edge[e], e1 = edge[E + e];
    int p = off[node2slot[e1]] + (int)rank16[e];
    float px = pos[3 * e0]     - pos[3 * e1];
    float py = pos[3 * e0 + 1] - pos[3 * e1 + 1];
    float pz = pos[3 * e0 + 2] - pos[3 * e1 + 2];
    float n0x = normal[3 * e0], n0y = normal[3 * e0 + 1], n0z = normal[3 * e0 + 2];
    float n1x = normal[3 * e1], n1y = normal[3 * e1 + 1], n1z = normal[3 * e1 + 2];
    float d  = sqrtf(px * px + py * py + pz * pz);
    float a1 = angle3(n1x, n1y, n1z, px, py, pz);
    float a2 = angle3(n0x, n0y, n0z, px, py, pz);
    float a3 = angle3(n1x, n1y, n1z, n0x, n0y, n0z);
    uint4 rec;
    rec.x = (unsigned)e0;
    rec.y = pk(d, a1);
    rec.z = pk(a2, a3);
    rec.w = 0;
    prec[p] = rec;
}

__device__ __forceinline__ void load_af(uint4 rec, const unsigned short* __restrict__ xbf,
                                        int quad, short8& a0, short8& a1, short8& a2) {
    const short8* xr = (const short8*)(xbf + (size_t)rec.x * F_DIM);
    a0 = xr[quad];          // k = quad*8 .. +8
    a1 = xr[4 + quad];      // k = 32 + quad*8 .. +8
    short8 z = (short8){0, 0, 0, 0, 0, 0, 0, 0};
    if (quad == 0) {        // k = 64..67 = ppf, 68..71 zero (wt2 rows 68+ are zero anyway)
        z[0] = (short)(rec.y & 0xffff); z[1] = (short)(rec.y >> 16);
        z[2] = (short)(rec.z & 0xffff); z[3] = (short)(rec.z >> 16);
    }
    a2 = z;
}

// wave-per-segment with dynamic queue (tail balance); dup slots recompute via node
// indirection (no finalize pass). __launch_bounds__(256,2): the ONLY regalloc regime
// that doesn't spill (VGPR ~88 needed; min-waves/EU=4 caps at 64 -> 200MB scratch,
// 2-4x slower. R6+R8 lessons.)
__global__ __launch_bounds__(256, 2)
void seg_kernel(const unsigned short* __restrict__ xbf, const unsigned short* __restrict__ wt2,
                const uint4* __restrict__ prec, const int* __restrict__ off,
                const int* __restrict__ cnt_node, const int* __restrict__ node2slot,
                const int* __restrict__ idx, int* __restrict__ qctr,
                float* __restrict__ out, int S) {
    __shared__ __align__(16) unsigned short w_lds[H_DIM * LW2];
    __shared__ int sdrain;
    if (threadIdx.x == 0) sdrain = atomicAdd(qctr, 0);    // peek: late blocks skip staging
    __syncthreads();
    if (sdrain >= S) return;
    {
        const uint4* src = (const uint4*)wt2;
        uint4* dst = (uint4*)w_lds;
        for (int g = threadIdx.x; g < H_DIM * LW2 / 8; g += 256) dst[g] = src[g];
    }
    __syncthreads();

    const int lane = threadIdx.x & 63;
    const int l15  = lane & 15;
    const int quad = lane >> 4;

    for (;;) {
        int sb = 0;
        if (lane == 0) sb = atomicAdd(qctr, QCH);
        sb = __shfl(sb, 0, 64);
        if (sb >= S) break;
        int se = sb + QCH; if (se > S) se = S;

        for (int s = sb; s < se; ++s) {
            const int node = idx[s];
            const int n = cnt_node[node];
            float* orow = out + (size_t)s * H_DIM;
            if (n == 0) {               // empty segment -> 0 (reference isfinite fixup)
                orow[lane] = 0.f;
                orow[64 + lane] = 0.f;
                continue;
            }
            const uint4* pb = prec + off[node2slot[node]];

            float rm[8];
            #pragma unroll
            for (int ct = 0; ct < 8; ++ct) rm[ct] = -FLT_MAX;

            const int ntile = (n + 15) >> 4;
            int r = l15; if (r >= n) r = n - 1;   // pad rows = real edge dup -> exact for max
            uint4 rec = pb[r];
            short8 a0c, a1c, a2c;
            load_af(rec, xbf, quad, a0c, a1c, a2c);

            for (int t = 0; t < ntile; ++t) {
                // prefetch next tile's record + A-frags (overlaps the MFMAs below)
                uint4 recn = rec;
                if (t + 1 < ntile) {
                    int rn = ((t + 1) << 4) + l15; if (rn >= n) rn = n - 1;
                    recn = pb[rn];
                }
                short8 a0n, a1n, a2n;
                load_af(recn, xbf, quad, a0n, a1n, a2n);

                f32x4 acc[8];
                #pragma unroll
                for (int ct = 0; ct < 8; ++ct) acc[ct] = (f32x4){0.f, 0.f, 0.f, 0.f};
                #pragma unroll
                for (int ct = 0; ct < 8; ++ct) {
                    const unsigned short* wc = w_lds + (ct * 16 + l15) * LW2 + (quad << 3);
                    short8 b0 = *(const short8*)(wc);
                    short8 b1 = *(const short8*)(wc + 32);
                    short8 b2 = *(const short8*)(wc + 64);
                    acc[ct] = __builtin_amdgcn_mfma_f32_16x16x32_bf16(a0c, b0, acc[ct], 0, 0, 0);
                    acc[ct] = __builtin_amdgcn_mfma_f32_16x16x32_bf16(a1c, b1, acc[ct], 0, 0, 0);
                    acc[ct] = __builtin_amdgcn_mfma_f32_16x16x32_bf16(a2c, b2, acc[ct], 0, 0, 0);
                }
                #pragma unroll
                for (int ct = 0; ct < 8; ++ct)
                    rm[ct] = fmaxf(rm[ct], fmaxf(fmaxf(acc[ct][0], acc[ct][1]),
                                                 fmaxf(acc[ct][2], acc[ct][3])));
                a0c = a0n; a1c = a1n; a2c = a2n; rec = recn;
            }

            #pragma unroll
            for (int ct = 0; ct < 8; ++ct) {
                rm[ct] = fmaxf(rm[ct], __shfl_xor(rm[ct], 16, 64));
                rm[ct] = fmaxf(rm[ct], __shfl_xor(rm[ct], 32, 64));
            }
            float v0 = rm[0], v1 = rm[4];   // col = ct*16 + l15; lane -> cols lane, lane+64
            if (quad == 1)      { v0 = rm[1]; v1 = rm[5]; }
            else if (quad == 2) { v0 = rm[2]; v1 = rm[6]; }
            else if (quad == 3) { v0 = rm[3]; v1 = rm[7]; }
            orow[lane]      = fmaxf(orow[lane] + v0, 0.f);    // c + max, relu (hoist exact)
            orow[64 + lane] = fmaxf(orow[64 + lane] + v1, 0.f);
        }
    }
}

extern "C" void kernel_launch(void* const* d_in, const int* in_sizes, int n_in,
                              void* d_out, int out_size, void* d_ws, size_t ws_size,
                              hipStream_t stream) {
    const float* x      = (const float*)d_in[0];
    const float* pos    = (const float*)d_in[1];
    const float* normal = (const float*)d_in[2];
    const float* W      = (const float*)d_in[3];
    const float* b      = (const float*)d_in[4];
    const int*   edge   = (const int*)d_in[5];
    const int*   idx    = (const int*)d_in[6];

    const int H = in_sizes[4];            // 128
    const int K = in_sizes[3] / H;        // 132
    const int F = (K - 4) / 2;            // 64
    const int N = in_sizes[0] / F;        // 100000
    const int E = in_sizes[5] / 2;        // 800000
    const int S = in_sizes[6];            // 25000

    // ws (256B aligned): wt2 | w1t | xbf[N*64]bf16 | prec[E]uint4 | node2slot[N]
    //                    | cnt_node[N+1] (last = scan total) | rank16[E] | off[S] | qctr
    char* p = (char*)d_ws;
    auto alloc = [&](size_t bytes) { char* r = p; p += (bytes + 255) & ~(size_t)255; return r; };
    unsigned short* wt2 = (unsigned short*)alloc((size_t)H_DIM * LW2 * sizeof(unsigned short));
    unsigned short* w1t = (unsigned short*)alloc((size_t)H_DIM * LW1 * sizeof(unsigned short));
    unsigned short* xbf = (unsigned short*)alloc((size_t)N * F_DIM * sizeof(unsigned short));
    uint4* prec         = (uint4*)alloc((size_t)E * sizeof(uint4));
    int* node2slot      = (int*)alloc((size_t)N * sizeof(int));
    int* cnt_node       = (int*)alloc((size_t)(N + 1) * sizeof(int));
    unsigned short* rank16 = (unsigned short*)alloc((size_t)E * sizeof(unsigned short));
    int* off            = (int*)alloc((size_t)S * sizeof(int));
    int* qctr           = (int*)alloc(sizeof(int));
    float* out = (float*)d_out;           // cmat writes c, seg RMWs to final result

    const int AB = (S + 255) / 256;
    const int CB = (S + 63) / 64;
    const int NF8 = N * F_DIM / 8;

    hipMemsetAsync(cnt_node, 0, (size_t)(N + 1) * sizeof(int), stream);
    prep0<<<2048, 256, 0, stream>>>(W, wt2, w1t, x, xbf, idx, node2slot, edge,
                                    cnt_node, rank16, pos, out, qctr, S, E, NF8);
    alloc_cmat<<<AB + CB, 256, 0, stream>>>(cnt_node, node2slot, off, cnt_node + N,
                                            xbf, w1t, b, idx, out, S, AB);
    place_kernel<<<(E + 255) / 256, 256, 0, stream>>>(edge, pos, normal, node2slot,
                                                      rank16, off, prec, E);
    seg_kernel<<<2048, 256, 0, stream>>>(xbf, wt2, prec, off, cnt_node, node2slot,
                                         idx, qctr, out, S);
}

// Round 10
// 231.813 us; speedup vs baseline: 1.7401x; 1.7401x over previous
//
#include <hip/hip_runtime.h>
#include <hip/hip_bf16.h>
#include <float.h>

#define F_DIM 64
#define H_DIM 128
#define LW2   104   // wt2 row stride (bf16) for K=96 [x[e0]|ppf|pad]: 208 B, 16B-aligned
#define LW1   72    // w1t row stride (bf16) for K=64 [x[e1]]: 144 B, 16B-aligned

typedef __attribute__((ext_vector_type(8))) short short8;   // 8 bf16 (mfma A/B frag)
typedef __attribute__((ext_vector_type(4))) float f32x4;    // mfma C/D frag

__device__ __forceinline__ unsigned short f2bf(float f) {
    __hip_bfloat16 h = __float2bfloat16(f);
    return __builtin_bit_cast(unsigned short, h);
}
__device__ __forceinline__ unsigned pk(float a, float b) {
    return (unsigned)f2bf(a) | ((unsigned)f2bf(b) << 16);
}

__device__ __forceinline__ float angle3(float ax, float ay, float az,
                                        float bx, float by, float bz) {
    float cx = ay*bz - az*by;
    float cy = az*bx - ax*bz;
    float cz = ax*by - ay*bx;
    float cn = sqrtf(cx*cx + cy*cy + cz*cz);
    float d  = ax*bx + ay*by + az*bz;
    return atan2f(cn, d);
}

// fused streaming pass: wt2 + w1t builds, xbf (x->bf16 mfma layout), node2slot scatter,
// per-NODE edge histogram with rank capture (atomic return is the free rank), pos tail.
// cnt_node must be zeroed (hipMemsetAsync) before this kernel.
__global__ __launch_bounds__(256)
void prep0(const float* __restrict__ W, unsigned short* __restrict__ wt2,
           unsigned short* __restrict__ w1t, const float* __restrict__ x,
           unsigned short* __restrict__ xbf, const int* __restrict__ idx,
           int* __restrict__ node2slot, const int* __restrict__ edge,
           int* __restrict__ cnt_node, unsigned short* __restrict__ rank16,
           const float* __restrict__ pos, float* __restrict__ out,
           int S, int E, int NF8) {
    const int T = gridDim.x * blockDim.x;
    const int gid = blockIdx.x * blockDim.x + threadIdx.x;
    for (int g = gid; g < NF8; g += T) {                  // x[N][64] f32 -> bf16, 8/thread
        const float4* s4 = (const float4*)x + (size_t)g * 2;
        float4 f0 = s4[0], f1 = s4[1];
        uint4 q;
        q.x = pk(f0.x, f0.y); q.y = pk(f0.z, f0.w);
        q.z = pk(f1.x, f1.y); q.w = pk(f1.z, f1.w);
        ((uint4*)xbf)[g] = q;
    }
    for (int g = gid; g < H_DIM * LW2; g += T) {          // W rows 64..131 -> [H][LW2]
        int h = g / LW2, k = g % LW2;
        float v = 0.f;
        if (k < F_DIM)          v = W[(F_DIM + k) * H_DIM + h];
        else if (k < F_DIM + 4) v = W[(2 * F_DIM + (k - F_DIM)) * H_DIM + h];
        wt2[g] = f2bf(v);
    }
    for (int g = gid; g < H_DIM * LW1; g += T) {          // W rows 0..63 -> [H][LW1]
        int h = g / LW1, k = g % LW1;
        w1t[g] = f2bf((k < F_DIM) ? W[k * H_DIM + h] : 0.f);
    }
    for (int g = gid; g < S; g += T) node2slot[idx[g]] = g;  // any winner = canonical slot
    for (int g = gid; g < E; g += T) {                       // per-node histogram + rank
        int e1 = edge[E + g];
        rank16[g] = (unsigned short)atomicAdd(&cnt_node[e1], 1);
    }
    for (int g = gid; g < 3 * S; g += T)                     // out tail = pos[idx]
        out[(size_t)S * H_DIM + g] = pos[(size_t)idx[g / 3] * 3 + (g % 3)];
}

// blocks [0,AB): per-slot range alloc (canonical slots carry their node's count) -> off.
// blocks [AB,AB+CB): cmat = b + x[idx]·W1 -> out
__global__ __launch_bounds__(256)
void alloc_cmat(const int* __restrict__ cnt_node, const int* __restrict__ node2slot,
                int* __restrict__ off, int* __restrict__ total,
                const unsigned short* __restrict__ xbf,
                const unsigned short* __restrict__ w1t, const float* __restrict__ bias,
                const int* __restrict__ idx, float* __restrict__ out, int S, int AB) {
    __shared__ int wsum[4];
    __shared__ int bb;
    __shared__ __align__(16) unsigned short a_lds[64 * LW1];
    const int tid = threadIdx.x;

    if ((int)blockIdx.x < AB) {
        int s = blockIdx.x * 256 + tid;
        int v = 0;
        if (s < S) {
            int node = idx[s];
            if (node2slot[node] == s) v = cnt_node[node];   // non-canonical dup slot -> 0
        }
        int lane = tid & 63, wv = tid >> 6;
        int sc = v;
        #pragma unroll
        for (int d = 1; d < 64; d <<= 1) {
            int t = __shfl_up(sc, d, 64);
            if (lane >= d) sc += t;
        }
        if (lane == 63) wsum[wv] = sc;
        __syncthreads();
        if (tid == 0) {
            int t = 0;
            #pragma unroll
            for (int i = 0; i < 4; ++i) { int w = wsum[i]; wsum[i] = t; t += w; }
            bb = atomicAdd(total, t);
        }
        __syncthreads();
        int excl = bb + wsum[wv] + sc - v;
        if (s < S) off[s] = excl;
        return;
    }

    // ---- cmat: 64 slots per block, A rows from xbf (already bf16) ----
    const int sbase = (blockIdx.x - AB) * 64;
    const int m = tid >> 2, p = tid & 3;
    {
        int s = sbase + m; if (s >= S) s = S - 1;
        int node = idx[s];
        const uint4* src = (const uint4*)(xbf + (size_t)node * F_DIM) + p * 2;
        uint4* dst = (uint4*)(a_lds + m * LW1 + p * 16);
        dst[0] = src[0]; dst[1] = src[1];
        if (p == 0) *(uint4*)(a_lds + m * LW1 + 64) = make_uint4(0, 0, 0, 0);
    }
    __syncthreads();
    const int wv = tid >> 6, lane = tid & 63, l15 = lane & 15, quad = lane >> 4;
    const int n0 = wv * 32 + l15, n1 = n0 + 16;
    f32x4 acc[4][2];
    #pragma unroll
    for (int i = 0; i < 4; ++i) {
        acc[i][0] = (f32x4){0.f, 0.f, 0.f, 0.f};
        acc[i][1] = (f32x4){0.f, 0.f, 0.f, 0.f};
    }
    #pragma unroll
    for (int ks = 0; ks < 2; ++ks) {
        const int ko = ks * 32 + quad * 8;
        short8 bf0 = *(const short8*)(w1t + (size_t)n0 * LW1 + ko);
        short8 bf1 = *(const short8*)(w1t + (size_t)n1 * LW1 + ko);
        #pragma unroll
        for (int mt = 0; mt < 4; ++mt) {
            short8 af = *(const short8*)(a_lds + (mt * 16 + l15) * LW1 + ko);
            acc[mt][0] = __builtin_amdgcn_mfma_f32_16x16x32_bf16(af, bf0, acc[mt][0], 0, 0, 0);
            acc[mt][1] = __builtin_amdgcn_mfma_f32_16x16x32_bf16(af, bf1, acc[mt][1], 0, 0, 0);
        }
    }
    const float b0 = bias[n0], b1 = bias[n1];
    #pragma unroll
    for (int mt = 0; mt < 4; ++mt) {
        #pragma unroll
        for (int r = 0; r < 4; ++r) {
            int s = sbase + mt * 16 + quad * 4 + r;     // C/D: row = quad*4 + reg
            if (s < S) {
                out[(size_t)s * H_DIM + n0] = acc[mt][0][r] + b0;
                out[(size_t)s * H_DIM + n1] = acc[mt][1][r] + b1;
            }
        }
    }
}

// ATOMIC-FREE placement: p = off[slot(e1)] + rank[e]; gathers + trig + one 16B record write.
__global__ void place_kernel(const int* __restrict__ edge, const float* __restrict__ pos,
                             const float* __restrict__ normal,
                             const int* __restrict__ node2slot,
                             const unsigned short* __restrict__ rank16,
                             const int* __restrict__ off, uint4* __restrict__ prec, int E) {
    int e = blockIdx.x * blockDim.x + threadIdx.x;
    if (e >= E) return;
    int e0 = edge[e], e1 = edge[E + e];
    int p = off[node2slot[e1]] + (int)rank16[e];
    float px = pos[3 * e0]     - pos[3 * e1];
    float py = pos[3 * e0 + 1] - pos[3 * e1 + 1];
    float pz = pos[3 * e0 + 2] - pos[3 * e1 + 2];
    float n0x = normal[3 * e0], n0y = normal[3 * e0 + 1], n0z = normal[3 * e0 + 2];
    float n1x = normal[3 * e1], n1y = normal[3 * e1 + 1], n1z = normal[3 * e1 + 2];
    float d  = sqrtf(px * px + py * py + pz * pz);
    float a1 = angle3(n1x, n1y, n1z, px, py, pz);
    float a2 = angle3(n0x, n0y, n0z, px, py, pz);
    float a3 = angle3(n1x, n1y, n1z, n0x, n0y, n0z);
    uint4 rec;
    rec.x = (unsigned)e0;
    rec.y = pk(d, a1);
    rec.z = pk(a2, a3);
    rec.w = 0;
    prec[p] = rec;
}

__device__ __forceinline__ void load_af(uint4 rec, const unsigned short* __restrict__ xbf,
                                        int quad, short8& a0, short8& a1, short8& a2) {
    const short8* xr = (const short8*)(xbf + (size_t)rec.x * F_DIM);
    a0 = xr[quad];          // k = quad*8 .. +8
    a1 = xr[4 + quad];      // k = 32 + quad*8 .. +8
    short8 z = (short8){0, 0, 0, 0, 0, 0, 0, 0};
    if (quad == 0) {        // k = 64..67 = ppf, 68..71 zero (wt2 rows 68+ are zero anyway)
        z[0] = (short)(rec.y & 0xffff); z[1] = (short)(rec.y >> 16);
        z[2] = (short)(rec.z & 0xffff); z[3] = (short)(rec.z >> 16);
    }
    a2 = z;
}

// wave-per-segment, STATIC interleaved assignment (R9 lesson: a single-counter dynamic
// queue = 12.5K serialized device atomics ≈ 250 µs — never again). Dup slots recompute
// via node indirection (no finalize pass). __launch_bounds__(256,2): the only clean
// regalloc regime (VGPR ~88 needed; min-waves/EU=4 caps at 64 -> spills. R6+R8 lessons.)
__global__ __launch_bounds__(256, 2)
void seg_kernel(const unsigned short* __restrict__ xbf, const unsigned short* __restrict__ wt2,
                const uint4* __restrict__ prec, const int* __restrict__ off,
                const int* __restrict__ cnt_node, const int* __restrict__ node2slot,
                const int* __restrict__ idx, float* __restrict__ out, int S) {
    __shared__ __align__(16) unsigned short w_lds[H_DIM * LW2];
    {
        const uint4* src = (const uint4*)wt2;
        uint4* dst = (uint4*)w_lds;
        for (int g = threadIdx.x; g < H_DIM * LW2 / 8; g += 256) dst[g] = src[g];
    }
    __syncthreads();

    const int tid  = threadIdx.x;
    const int wv   = tid >> 6;
    const int lane = tid & 63;
    const int l15  = lane & 15;
    const int quad = lane >> 4;
    const int nw   = gridDim.x << 2;

    for (int s = (blockIdx.x << 2) + wv; s < S; s += nw) {
        const int node = idx[s];
        const int n = cnt_node[node];
        float* orow = out + (size_t)s * H_DIM;
        if (n == 0) {                   // empty segment -> 0 (reference isfinite fixup)
            orow[lane] = 0.f;
            orow[64 + lane] = 0.f;
            continue;
        }
        const uint4* pb = prec + off[node2slot[node]];

        float rm[8];
        #pragma unroll
        for (int ct = 0; ct < 8; ++ct) rm[ct] = -FLT_MAX;

        const int ntile = (n + 15) >> 4;
        int r = l15; if (r >= n) r = n - 1;   // pad rows = real edge dup -> exact for max
        uint4 rec = pb[r];
        short8 a0c, a1c, a2c;
        load_af(rec, xbf, quad, a0c, a1c, a2c);

        for (int t = 0; t < ntile; ++t) {
            // prefetch next tile's record + A-frags (overlaps the MFMAs below)
            uint4 recn = rec;
            if (t + 1 < ntile) {
                int rn = ((t + 1) << 4) + l15; if (rn >= n) rn = n - 1;
                recn = pb[rn];
            }
            short8 a0n, a1n, a2n;
            load_af(recn, xbf, quad, a0n, a1n, a2n);

            f32x4 acc[8];
            #pragma unroll
            for (int ct = 0; ct < 8; ++ct) acc[ct] = (f32x4){0.f, 0.f, 0.f, 0.f};
            #pragma unroll
            for (int ct = 0; ct < 8; ++ct) {
                const unsigned short* wc = w_lds + (ct * 16 + l15) * LW2 + (quad << 3);
                short8 b0 = *(const short8*)(wc);
                short8 b1 = *(const short8*)(wc + 32);
                short8 b2 = *(const short8*)(wc + 64);
                acc[ct] = __builtin_amdgcn_mfma_f32_16x16x32_bf16(a0c, b0, acc[ct], 0, 0, 0);
                acc[ct] = __builtin_amdgcn_mfma_f32_16x16x32_bf16(a1c, b1, acc[ct], 0, 0, 0);
                acc[ct] = __builtin_amdgcn_mfma_f32_16x16x32_bf16(a2c, b2, acc[ct], 0, 0, 0);
            }
            #pragma unroll
            for (int ct = 0; ct < 8; ++ct)
                rm[ct] = fmaxf(rm[ct], fmaxf(fmaxf(acc[ct][0], acc[ct][1]),
                                             fmaxf(acc[ct][2], acc[ct][3])));
            a0c = a0n; a1c = a1n; a2c = a2n; rec = recn;
        }

        #pragma unroll
        for (int ct = 0; ct < 8; ++ct) {
            rm[ct] = fmaxf(rm[ct], __shfl_xor(rm[ct], 16, 64));
            rm[ct] = fmaxf(rm[ct], __shfl_xor(rm[ct], 32, 64));
        }
        float v0 = rm[0], v1 = rm[4];   // col = ct*16 + l15; lane -> cols lane, lane+64
        if (quad == 1)      { v0 = rm[1]; v1 = rm[5]; }
        else if (quad == 2) { v0 = rm[2]; v1 = rm[6]; }
        else if (quad == 3) { v0 = rm[3]; v1 = rm[7]; }
        orow[lane]      = fmaxf(orow[lane] + v0, 0.f);    // c + max, relu (hoist exact)
        orow[64 + lane] = fmaxf(orow[64 + lane] + v1, 0.f);
    }
}

extern "C" void kernel_launch(void* const* d_in, const int* in_sizes, int n_in,
                              void* d_out, int out_size, void* d_ws, size_t ws_size,
                              hipStream_t stream) {
    const float* x      = (const float*)d_in[0];
    const float* pos    = (const float*)d_in[1];
    const float* normal = (const float*)d_in[2];
    const float* W      = (const float*)d_in[3];
    const float* b      = (const float*)d_in[4];
    const int*   edge   = (const int*)d_in[5];
    const int*   idx    = (const int*)d_in[6];

    const int H = in_sizes[4];            // 128
    const int K = in_sizes[3] / H;        // 132
    const int F = (K - 4) / 2;            // 64
    const int N = in_sizes[0] / F;        // 100000
    const int E = in_sizes[5] / 2;        // 800000
    const int S = in_sizes[6];            // 25000

    // ws (256B aligned): wt2 | w1t | xbf[N*64]bf16 | prec[E]uint4 | node2slot[N]
    //                    | cnt_node[N+1] (last = scan total) | rank16[E] | off[S]
    char* p = (char*)d_ws;
    auto alloc = [&](size_t bytes) { char* r = p; p += (bytes + 255) & ~(size_t)255; return r; };
    unsigned short* wt2 = (unsigned short*)alloc((size_t)H_DIM * LW2 * sizeof(unsigned short));
    unsigned short* w1t = (unsigned short*)alloc((size_t)H_DIM * LW1 * sizeof(unsigned short));
    unsigned short* xbf = (unsigned short*)alloc((size_t)N * F_DIM * sizeof(unsigned short));
    uint4* prec         = (uint4*)alloc((size_t)E * sizeof(uint4));
    int* node2slot      = (int*)alloc((size_t)N * sizeof(int));
    int* cnt_node       = (int*)alloc((size_t)(N + 1) * sizeof(int));
    unsigned short* rank16 = (unsigned short*)alloc((size_t)E * sizeof(unsigned short));
    int* off            = (int*)alloc((size_t)S * sizeof(int));
    float* out = (float*)d_out;           // cmat writes c, seg RMWs to final result

    const int AB = (S + 255) / 256;
    const int CB = (S + 63) / 64;
    const int NF8 = N * F_DIM / 8;

    hipMemsetAsync(cnt_node, 0, (size_t)(N + 1) * sizeof(int), stream);
    prep0<<<2048, 256, 0, stream>>>(W, wt2, w1t, x, xbf, idx, node2slot, edge,
                                    cnt_node, rank16, pos, out, S, E, NF8);
    alloc_cmat<<<AB + CB, 256, 0, stream>>>(cnt_node, node2slot, off, cnt_node + N,
                                            xbf, w1t, b, idx, out, S, AB);
    place_kernel<<<(E + 255) / 256, 256, 0, stream>>>(edge, pos, normal, node2slot,
                                                      rank16, off, prec, E);
    seg_kernel<<<2048, 256, 0, stream>>>(xbf, wt2, prec, off, cnt_node, node2slot,
                                         idx, out, S);
}

// Round 11
// 224.274 us; speedup vs baseline: 1.7986x; 1.0336x over previous
//
#include <hip/hip_runtime.h>
#include <hip/hip_bf16.h>
#include <float.h>

#define F_DIM 64
#define H_DIM 128
#define LW2   104   // wt2 row stride (bf16) for K=96 [x[e0]|ppf|pad]: 208 B, 16B-aligned
#define LW1   72    // w1t row stride (bf16) for K=64 [x[e1]]: 144 B, 16B-aligned
#define CPAD  16    // ints per histogram counter: one 64B line each (atomic contention fix)

typedef __attribute__((ext_vector_type(8))) short short8;   // 8 bf16 (mfma A/B frag)
typedef __attribute__((ext_vector_type(4))) float f32x4;    // mfma C/D frag

__device__ __forceinline__ unsigned short f2bf(float f) {
    __hip_bfloat16 h = __float2bfloat16(f);
    return __builtin_bit_cast(unsigned short, h);
}
__device__ __forceinline__ unsigned pk(float a, float b) {
    return (unsigned)f2bf(a) | ((unsigned)f2bf(b) << 16);
}

__device__ __forceinline__ float angle3(float ax, float ay, float az,
                                        float bx, float by, float bz) {
    float cx = ay*bz - az*by;
    float cy = az*bx - ax*bz;
    float cz = ax*by - ay*bx;
    float cn = sqrtf(cx*cx + cy*cy + cz*cz);
    float d  = ax*bx + ay*by + az*bz;
    return atan2f(cn, d);
}

// fused streaming pass: wt2 + w1t builds, xbf (x->bf16 mfma layout), node2slot scatter,
// per-NODE edge histogram with rank capture (line-padded counters), pos tail.
// cnt must be zeroed before this kernel. Grid 1024: measured faster than 2048 (R7 vs R10
// — more waves worsened atomic contention).
__global__ __launch_bounds__(256)
void prep0(const float* __restrict__ W, unsigned short* __restrict__ wt2,
           unsigned short* __restrict__ w1t, const float* __restrict__ x,
           unsigned short* __restrict__ xbf, const int* __restrict__ idx,
           int* __restrict__ node2slot, const int* __restrict__ edge,
           int* __restrict__ cnt, unsigned short* __restrict__ rank16,
           const float* __restrict__ pos, float* __restrict__ out,
           int S, int E, int NF8) {
    const int T = gridDim.x * blockDim.x;
    const int gid = blockIdx.x * blockDim.x + threadIdx.x;
    for (int g = gid; g < NF8; g += T) {                  // x[N][64] f32 -> bf16, 8/thread
        const float4* s4 = (const float4*)x + (size_t)g * 2;
        float4 f0 = s4[0], f1 = s4[1];
        uint4 q;
        q.x = pk(f0.x, f0.y); q.y = pk(f0.z, f0.w);
        q.z = pk(f1.x, f1.y); q.w = pk(f1.z, f1.w);
        ((uint4*)xbf)[g] = q;
    }
    for (int g = gid; g < H_DIM * LW2; g += T) {          // W rows 64..131 -> [H][LW2]
        int h = g / LW2, k = g % LW2;
        float v = 0.f;
        if (k < F_DIM)          v = W[(F_DIM + k) * H_DIM + h];
        else if (k < F_DIM + 4) v = W[(2 * F_DIM + (k - F_DIM)) * H_DIM + h];
        wt2[g] = f2bf(v);
    }
    for (int g = gid; g < H_DIM * LW1; g += T) {          // W rows 0..63 -> [H][LW1]
        int h = g / LW1, k = g % LW1;
        w1t[g] = f2bf((k < F_DIM) ? W[k * H_DIM + h] : 0.f);
    }
    for (int g = gid; g < S; g += T) node2slot[idx[g]] = g;  // any winner = canonical slot
    for (int g = gid; g < E; g += T) {                       // per-node histogram + rank
        int e1 = edge[E + g];
        rank16[g] = (unsigned short)atomicAdd(&cnt[(size_t)e1 * CPAD], 1);
    }
    for (int g = gid; g < 3 * S; g += T)                     // out tail = pos[idx]
        out[(size_t)S * H_DIM + g] = pos[(size_t)idx[g / 3] * 3 + (g % 3)];
}

// blocks [0,AB): per-slot range alloc (canonical slots carry their node's count) -> off.
// blocks [AB,AB+CB): cmat = b + x[idx]·W1 -> out
__global__ __launch_bounds__(256)
void alloc_cmat(const int* __restrict__ cnt, const int* __restrict__ node2slot,
                int* __restrict__ off, int* __restrict__ total,
                const unsigned short* __restrict__ xbf,
                const unsigned short* __restrict__ w1t, const float* __restrict__ bias,
                const int* __restrict__ idx, float* __restrict__ out, int S, int AB) {
    __shared__ int wsum[4];
    __shared__ int bb;
    __shared__ __align__(16) unsigned short a_lds[64 * LW1];
    const int tid = threadIdx.x;

    if ((int)blockIdx.x < AB) {
        int s = blockIdx.x * 256 + tid;
        int v = 0;
        if (s < S) {
            int node = idx[s];
            if (node2slot[node] == s) v = cnt[(size_t)node * CPAD];  // non-canonical -> 0
        }
        int lane = tid & 63, wv = tid >> 6;
        int sc = v;
        #pragma unroll
        for (int d = 1; d < 64; d <<= 1) {
            int t = __shfl_up(sc, d, 64);
            if (lane >= d) sc += t;
        }
        if (lane == 63) wsum[wv] = sc;
        __syncthreads();
        if (tid == 0) {
            int t = 0;
            #pragma unroll
            for (int i = 0; i < 4; ++i) { int w = wsum[i]; wsum[i] = t; t += w; }
            bb = atomicAdd(total, t);
        }
        __syncthreads();
        int excl = bb + wsum[wv] + sc - v;
        if (s < S) off[s] = excl;
        return;
    }

    // ---- cmat: 64 slots per block, A rows from xbf (already bf16) ----
    const int sbase = (blockIdx.x - AB) * 64;
    const int m = tid >> 2, p = tid & 3;
    {
        int s = sbase + m; if (s >= S) s = S - 1;
        int node = idx[s];
        const uint4* src = (const uint4*)(xbf + (size_t)node * F_DIM) + p * 2;
        uint4* dst = (uint4*)(a_lds + m * LW1 + p * 16);
        dst[0] = src[0]; dst[1] = src[1];
        if (p == 0) *(uint4*)(a_lds + m * LW1 + 64) = make_uint4(0, 0, 0, 0);
    }
    __syncthreads();
    const int wv = tid >> 6, lane = tid & 63, l15 = lane & 15, quad = lane >> 4;
    const int n0 = wv * 32 + l15, n1 = n0 + 16;
    f32x4 acc[4][2];
    #pragma unroll
    for (int i = 0; i < 4; ++i) {
        acc[i][0] = (f32x4){0.f, 0.f, 0.f, 0.f};
        acc[i][1] = (f32x4){0.f, 0.f, 0.f, 0.f};
    }
    #pragma unroll
    for (int ks = 0; ks < 2; ++ks) {
        const int ko = ks * 32 + quad * 8;
        short8 bf0 = *(const short8*)(w1t + (size_t)n0 * LW1 + ko);
        short8 bf1 = *(const short8*)(w1t + (size_t)n1 * LW1 + ko);
        #pragma unroll
        for (int mt = 0; mt < 4; ++mt) {
            short8 af = *(const short8*)(a_lds + (mt * 16 + l15) * LW1 + ko);
            acc[mt][0] = __builtin_amdgcn_mfma_f32_16x16x32_bf16(af, bf0, acc[mt][0], 0, 0, 0);
            acc[mt][1] = __builtin_amdgcn_mfma_f32_16x16x32_bf16(af, bf1, acc[mt][1], 0, 0, 0);
        }
    }
    const float b0 = bias[n0], b1 = bias[n1];
    #pragma unroll
    for (int mt = 0; mt < 4; ++mt) {
        #pragma unroll
        for (int r = 0; r < 4; ++r) {
            int s = sbase + mt * 16 + quad * 4 + r;     // C/D: row = quad*4 + reg
            if (s < S) {
                out[(size_t)s * H_DIM + n0] = acc[mt][0][r] + b0;
                out[(size_t)s * H_DIM + n1] = acc[mt][1][r] + b1;
            }
        }
    }
}

// threads [0,E): ATOMIC-FREE placement p = off[slot(e1)] + rank[e] -> 16B record.
// threads [E,E+S): snfo[s] = {off[canonical(s)], n} so seg's startup is ONE 8B load.
__global__ void place_kernel(const int* __restrict__ edge, const float* __restrict__ pos,
                             const float* __restrict__ normal,
                             const int* __restrict__ node2slot,
                             const unsigned short* __restrict__ rank16,
                             const int* __restrict__ off, const int* __restrict__ cnt,
                             const int* __restrict__ idx, uint4* __restrict__ prec,
                             int2* __restrict__ snfo, int E, int S) {
    int g = blockIdx.x * blockDim.x + threadIdx.x;
    if (g >= E) {
        int s = g - E;
        if (s < S) {
            int node = idx[s];
            snfo[s] = make_int2(off[node2slot[node]], cnt[(size_t)node * CPAD]);
        }
        return;
    }
    int e0 = edge[g], e1 = edge[E + g];
    int p = off[node2slot[e1]] + (int)rank16[g];
    float px = pos[3 * e0]     - pos[3 * e1];
    float py = pos[3 * e0 + 1] - pos[3 * e1 + 1];
    float pz = pos[3 * e0 + 2] - pos[3 * e1 + 2];
    float n0x = normal[3 * e0], n0y = normal[3 * e0 + 1], n0z = normal[3 * e0 + 2];
    float n1x = normal[3 * e1], n1y = normal[3 * e1 + 1], n1z = normal[3 * e1 + 2];
    float d  = sqrtf(px * px + py * py + pz * pz);
    float a1 = angle3(n1x, n1y, n1z, px, py, pz);
    float a2 = angle3(n0x, n0y, n0z, px, py, pz);
    float a3 = angle3(n1x, n1y, n1z, n0x, n0y, n0z);
    uint4 rec;
    rec.x = (unsigned)e0;
    rec.y = pk(d, a1);
    rec.z = pk(a2, a3);
    rec.w = 0;
    prec[p] = rec;
}

__device__ __forceinline__ void load_af(uint4 rec, const unsigned short* __restrict__ xbf,
                                        int quad, short8& a0, short8& a1, short8& a2) {
    const short8* xr = (const short8*)(xbf + (size_t)rec.x * F_DIM);
    a0 = xr[quad];          // k = quad*8 .. +8
    a1 = xr[4 + quad];      // k = 32 + quad*8 .. +8
    short8 z = (short8){0, 0, 0, 0, 0, 0, 0, 0};
    if (quad == 0) {        // k = 64..67 = ppf, 68..71 zero (wt2 rows 68+ are zero anyway)
        z[0] = (short)(rec.y & 0xffff); z[1] = (short)(rec.y >> 16);
        z[2] = (short)(rec.z & 0xffff); z[3] = (short)(rec.z >> 16);
    }
    a2 = z;
}

// wave-per-segment, STATIC interleaved assignment (R9: single-counter dynamic queue =
// 12.5K serialized device atomics ≈ 250 µs — never again). Segment startup = one int2
// load (snfo). Dup slots recompute (same n/base as canonical). __launch_bounds__(256,2):
// the only clean regalloc regime (~88 VGPR needed; waves/EU=4 caps at 64 -> spills).
__global__ __launch_bounds__(256, 2)
void seg_kernel(const unsigned short* __restrict__ xbf, const unsigned short* __restrict__ wt2,
                const uint4* __restrict__ prec, const int2* __restrict__ snfo,
                float* __restrict__ out, int S) {
    __shared__ __align__(16) unsigned short w_lds[H_DIM * LW2];
    {
        const uint4* src = (const uint4*)wt2;
        uint4* dst = (uint4*)w_lds;
        for (int g = threadIdx.x; g < H_DIM * LW2 / 8; g += 256) dst[g] = src[g];
    }
    __syncthreads();

    const int tid  = threadIdx.x;
    const int wv   = tid >> 6;
    const int lane = tid & 63;
    const int l15  = lane & 15;
    const int quad = lane >> 4;
    const int nw   = gridDim.x << 2;

    for (int s = (blockIdx.x << 2) + wv; s < S; s += nw) {
        const int2 nf = snfo[s];
        const int n = nf.y;
        float* orow = out + (size_t)s * H_DIM;
        if (n == 0) {                   // empty segment -> 0 (reference isfinite fixup)
            orow[lane] = 0.f;
            orow[64 + lane] = 0.f;
            continue;
        }
        const uint4* pb = prec + nf.x;

        float rm[8];
        #pragma unroll
        for (int ct = 0; ct < 8; ++ct) rm[ct] = -FLT_MAX;

        const int ntile = (n + 15) >> 4;
        int r = l15; if (r >= n) r = n - 1;   // pad rows = real edge dup -> exact for max
        uint4 rec = pb[r];
        short8 a0c, a1c, a2c;
        load_af(rec, xbf, quad, a0c, a1c, a2c);

        for (int t = 0; t < ntile; ++t) {
            // prefetch next tile's record + A-frags (overlaps the MFMAs below)
            uint4 recn = rec;
            if (t + 1 < ntile) {
                int rn = ((t + 1) << 4) + l15; if (rn >= n) rn = n - 1;
                recn = pb[rn];
            }
            short8 a0n, a1n, a2n;
            load_af(recn, xbf, quad, a0n, a1n, a2n);

            f32x4 acc[8];
            #pragma unroll
            for (int ct = 0; ct < 8; ++ct) acc[ct] = (f32x4){0.f, 0.f, 0.f, 0.f};
            #pragma unroll
            for (int ct = 0; ct < 8; ++ct) {
                const unsigned short* wc = w_lds + (ct * 16 + l15) * LW2 + (quad << 3);
                short8 b0 = *(const short8*)(wc);
                short8 b1 = *(const short8*)(wc + 32);
                short8 b2 = *(const short8*)(wc + 64);
                acc[ct] = __builtin_amdgcn_mfma_f32_16x16x32_bf16(a0c, b0, acc[ct], 0, 0, 0);
                acc[ct] = __builtin_amdgcn_mfma_f32_16x16x32_bf16(a1c, b1, acc[ct], 0, 0, 0);
                acc[ct] = __builtin_amdgcn_mfma_f32_16x16x32_bf16(a2c, b2, acc[ct], 0, 0, 0);
            }
            #pragma unroll
            for (int ct = 0; ct < 8; ++ct)
                rm[ct] = fmaxf(rm[ct], fmaxf(fmaxf(acc[ct][0], acc[ct][1]),
                                             fmaxf(acc[ct][2], acc[ct][3])));
            a0c = a0n; a1c = a1n; a2c = a2n; rec = recn;
        }

        #pragma unroll
        for (int ct = 0; ct < 8; ++ct) {
            rm[ct] = fmaxf(rm[ct], __shfl_xor(rm[ct], 16, 64));
            rm[ct] = fmaxf(rm[ct], __shfl_xor(rm[ct], 32, 64));
        }
        float v0 = rm[0], v1 = rm[4];   // col = ct*16 + l15; lane -> cols lane, lane+64
        if (quad == 1)      { v0 = rm[1]; v1 = rm[5]; }
        else if (quad == 2) { v0 = rm[2]; v1 = rm[6]; }
        else if (quad == 3) { v0 = rm[3]; v1 = rm[7]; }
        orow[lane]      = fmaxf(orow[lane] + v0, 0.f);    // c + max, relu (hoist exact)
        orow[64 + lane] = fmaxf(orow[64 + lane] + v1, 0.f);
    }
}

extern "C" void kernel_launch(void* const* d_in, const int* in_sizes, int n_in,
                              void* d_out, int out_size, void* d_ws, size_t ws_size,
                              hipStream_t stream) {
    const float* x      = (const float*)d_in[0];
    const float* pos    = (const float*)d_in[1];
    const float* normal = (const float*)d_in[2];
    const float* W      = (const float*)d_in[3];
    const float* b      = (const float*)d_in[4];
    const int*   edge   = (const int*)d_in[5];
    const int*   idx    = (const int*)d_in[6];

    const int H = in_sizes[4];            // 128
    const int K = in_sizes[3] / H;        // 132
    const int F = (K - 4) / 2;            // 64
    const int N = in_sizes[0] / F;        // 100000
    const int E = in_sizes[5] / 2;        // 800000
    const int S = in_sizes[6];            // 25000

    // ws (256B aligned): wt2 | w1t | xbf[N*64]bf16 | prec[E]uint4 | node2slot[N]
    //                    | cnt[N*CPAD+1] (line-padded; last = scan total) | rank16[E]
    //                    | off[S] | snfo[S]int2       (~37 MB total)
    char* p = (char*)d_ws;
    auto alloc = [&](size_t bytes) { char* r = p; p += (bytes + 255) & ~(size_t)255; return r; };
    unsigned short* wt2 = (unsigned short*)alloc((size_t)H_DIM * LW2 * sizeof(unsigned short));
    unsigned short* w1t = (unsigned short*)alloc((size_t)H_DIM * LW1 * sizeof(unsigned short));
    unsigned short* xbf = (unsigned short*)alloc((size_t)N * F_DIM * sizeof(unsigned short));
    uint4* prec         = (uint4*)alloc((size_t)E * sizeof(uint4));
    int* node2slot      = (int*)alloc((size_t)N * sizeof(int));
    int* cnt            = (int*)alloc(((size_t)N * CPAD + 1) * sizeof(int));
    unsigned short* rank16 = (unsigned short*)alloc((size_t)E * sizeof(unsigned short));
    int* off            = (int*)alloc((size_t)S * sizeof(int));
    int2* snfo          = (int2*)alloc((size_t)S * sizeof(int2));
    float* out = (float*)d_out;           // cmat writes c, seg RMWs to final result

    const int AB = (S + 255) / 256;
    const int CB = (S + 63) / 64;
    const int NF8 = N * F_DIM / 8;

    hipMemsetAsync(cnt, 0, ((size_t)N * CPAD + 1) * sizeof(int), stream);
    prep0<<<1024, 256, 0, stream>>>(W, wt2, w1t, x, xbf, idx, node2slot, edge,
                                    cnt, rank16, pos, out, S, E, NF8);
    alloc_cmat<<<AB + CB, 256, 0, stream>>>(cnt, node2slot, off, cnt + (size_t)N * CPAD,
                                            xbf, w1t, b, idx, out, S, AB);
    place_kernel<<<(E + S + 255) / 256, 256, 0, stream>>>(edge, pos, normal, node2slot,
                                                          rank16, off, cnt, idx,
                                                          prec, snfo, E, S);
    seg_kernel<<<2048, 256, 0, stream>>>(xbf, wt2, prec, snfo, out, S);
}

// Round 12
// 219.713 us; speedup vs baseline: 1.8359x; 1.0208x over previous
//
#include <hip/hip_runtime.h>
#include <hip/hip_bf16.h>
#include <float.h>

#define F_DIM 64
#define H_DIM 128
#define LW2   104   // wt2 row stride (bf16) for K=96 [x[e0]|ppf|pad]: 208 B, 16B-aligned
#define LW1   72    // w1t row stride (bf16) for K=64 [x[e1]]: 144 B, 16B-aligned
#define NB    128   // histogram blocks (counting-sort partitions)
#define SMAX  25600 // max slots supported by the LDS histogram (100 KB of 160 KB/CU)

typedef __attribute__((ext_vector_type(8))) short short8;   // 8 bf16 (mfma A/B frag)
typedef __attribute__((ext_vector_type(4))) float f32x4;    // mfma C/D frag

__device__ __forceinline__ unsigned short f2bf(float f) {
    __hip_bfloat16 h = __float2bfloat16(f);
    return __builtin_bit_cast(unsigned short, h);
}
__device__ __forceinline__ unsigned pk(float a, float b) {
    return (unsigned)f2bf(a) | ((unsigned)f2bf(b) << 16);
}

__device__ __forceinline__ float angle3(float ax, float ay, float az,
                                        float bx, float by, float bz) {
    float cx = ay*bz - az*by;
    float cy = az*bx - ax*bz;
    float cz = ax*by - ay*bx;
    float cn = sqrtf(cx*cx + cy*cy + cz*cz);
    float d  = ax*bx + ay*by + az*bz;
    return atan2f(cn, d);
}

// pure streaming pass, ZERO atomics (R11 lesson: 800K device atomics ≈ 40-50 µs floor;
// the histogram moved to LDS counting sort): wt2 + w1t builds, xbf (x->bf16 mfma
// layout), node2slot scatter, pos tail.
__global__ __launch_bounds__(256)
void prep0(const float* __restrict__ W, unsigned short* __restrict__ wt2,
           unsigned short* __restrict__ w1t, const float* __restrict__ x,
           unsigned short* __restrict__ xbf, const int* __restrict__ idx,
           int* __restrict__ node2slot, const float* __restrict__ pos,
           float* __restrict__ out, int S, int NF8) {
    const int T = gridDim.x * blockDim.x;
    const int gid = blockIdx.x * blockDim.x + threadIdx.x;
    for (int g = gid; g < NF8; g += T) {                  // x[N][64] f32 -> bf16, 8/thread
        const float4* s4 = (const float4*)x + (size_t)g * 2;
        float4 f0 = s4[0], f1 = s4[1];
        uint4 q;
        q.x = pk(f0.x, f0.y); q.y = pk(f0.z, f0.w);
        q.z = pk(f1.x, f1.y); q.w = pk(f1.z, f1.w);
        ((uint4*)xbf)[g] = q;
    }
    for (int g = gid; g < H_DIM * LW2; g += T) {          // W rows 64..131 -> [H][LW2]
        int h = g / LW2, k = g % LW2;
        float v = 0.f;
        if (k < F_DIM)          v = W[(F_DIM + k) * H_DIM + h];
        else if (k < F_DIM + 4) v = W[(2 * F_DIM + (k - F_DIM)) * H_DIM + h];
        wt2[g] = f2bf(v);
    }
    for (int g = gid; g < H_DIM * LW1; g += T) {          // W rows 0..63 -> [H][LW1]
        int h = g / LW1, k = g % LW1;
        w1t[g] = f2bf((k < F_DIM) ? W[k * H_DIM + h] : 0.f);
    }
    for (int g = gid; g < S; g += T) node2slot[idx[g]] = g;  // any winner = canonical slot
    for (int g = gid; g < 3 * S; g += T)                     // out tail = pos[idx]
        out[(size_t)S * H_DIM + g] = pos[(size_t)idx[g / 3] * 3 + (g % 3)];
}

// block-local LDS histogram over slots: block b counts its edge chunk in LDS (fast
// atomics, return = local rank), then dumps its counts row. Stable counting sort
// phase 1. LDS atomic >> L2 atomic throughput.
__global__ __launch_bounds__(1024)
void hist_kernel(const int* __restrict__ edge, const int* __restrict__ node2slot,
                 unsigned short* __restrict__ rank16, int* __restrict__ counts,
                 int E, int S, int chunk) {
    __shared__ int hcnt[SMAX];
    for (int i = threadIdx.x; i < S; i += 1024) hcnt[i] = 0;
    __syncthreads();
    const int base = blockIdx.x * chunk;
    int end = base + chunk; if (end > E) end = E;
    for (int e = base + (int)threadIdx.x; e < end; e += 1024) {
        int s = node2slot[edge[E + e]];     // every e1 is sampled -> canonical slot
        rank16[e] = (unsigned short)atomicAdd(&hcnt[s], 1);
    }
    __syncthreads();
    int* crow = counts + (size_t)blockIdx.x * S;
    for (int i = threadIdx.x; i < S; i += 1024) crow[i] = hcnt[i];
}

// counting sort phase 2: per-slot exclusive scan across block rows (coalesced).
// counts[b][s] becomes block b's base within segment s; nseg[s] = total.
// Non-canonical dup slots get nseg=0 automatically (no edge maps to them).
__global__ void colscan(int* __restrict__ counts, int* __restrict__ nseg, int S) {
    int s = blockIdx.x * blockDim.x + threadIdx.x;
    if (s >= S) return;
    int acc = 0;
    for (int b = 0; b < NB; ++b) {
        int c = counts[(size_t)b * S + s];
        counts[(size_t)b * S + s] = acc;
        acc += c;
    }
    nseg[s] = acc;
}

// blocks [0,AB): prefix over slots of nseg -> off. blocks [AB,AB+CB): cmat -> out
__global__ __launch_bounds__(256)
void alloc_cmat(const int* __restrict__ nseg, int* __restrict__ off,
                int* __restrict__ total, const unsigned short* __restrict__ xbf,
                const unsigned short* __restrict__ w1t, const float* __restrict__ bias,
                const int* __restrict__ idx, float* __restrict__ out, int S, int AB) {
    __shared__ int wsum[4];
    __shared__ int bb;
    __shared__ __align__(16) unsigned short a_lds[64 * LW1];
    const int tid = threadIdx.x;

    if ((int)blockIdx.x < AB) {
        int s = blockIdx.x * 256 + tid;
        int v = (s < S) ? nseg[s] : 0;
        int lane = tid & 63, wv = tid >> 6;
        int sc = v;
        #pragma unroll
        for (int d = 1; d < 64; d <<= 1) {
            int t = __shfl_up(sc, d, 64);
            if (lane >= d) sc += t;
        }
        if (lane == 63) wsum[wv] = sc;
        __syncthreads();
        if (tid == 0) {
            int t = 0;
            #pragma unroll
            for (int i = 0; i < 4; ++i) { int w = wsum[i]; wsum[i] = t; t += w; }
            bb = atomicAdd(total, t);
        }
        __syncthreads();
        int excl = bb + wsum[wv] + sc - v;
        if (s < S) off[s] = excl;
        return;
    }

    // ---- cmat: 64 slots per block, A rows from xbf (already bf16) ----
    const int sbase = (blockIdx.x - AB) * 64;
    const int m = tid >> 2, p = tid & 3;
    {
        int s = sbase + m; if (s >= S) s = S - 1;
        int node = idx[s];
        const uint4* src = (const uint4*)(xbf + (size_t)node * F_DIM) + p * 2;
        uint4* dst = (uint4*)(a_lds + m * LW1 + p * 16);
        dst[0] = src[0]; dst[1] = src[1];
        if (p == 0) *(uint4*)(a_lds + m * LW1 + 64) = make_uint4(0, 0, 0, 0);
    }
    __syncthreads();
    const int wv = tid >> 6, lane = tid & 63, l15 = lane & 15, quad = lane >> 4;
    const int n0 = wv * 32 + l15, n1 = n0 + 16;
    f32x4 acc[4][2];
    #pragma unroll
    for (int i = 0; i < 4; ++i) {
        acc[i][0] = (f32x4){0.f, 0.f, 0.f, 0.f};
        acc[i][1] = (f32x4){0.f, 0.f, 0.f, 0.f};
    }
    #pragma unroll
    for (int ks = 0; ks < 2; ++ks) {
        const int ko = ks * 32 + quad * 8;
        short8 bf0 = *(const short8*)(w1t + (size_t)n0 * LW1 + ko);
        short8 bf1 = *(const short8*)(w1t + (size_t)n1 * LW1 + ko);
        #pragma unroll
        for (int mt = 0; mt < 4; ++mt) {
            short8 af = *(const short8*)(a_lds + (mt * 16 + l15) * LW1 + ko);
            acc[mt][0] = __builtin_amdgcn_mfma_f32_16x16x32_bf16(af, bf0, acc[mt][0], 0, 0, 0);
            acc[mt][1] = __builtin_amdgcn_mfma_f32_16x16x32_bf16(af, bf1, acc[mt][1], 0, 0, 0);
        }
    }
    const float b0 = bias[n0], b1 = bias[n1];
    #pragma unroll
    for (int mt = 0; mt < 4; ++mt) {
        #pragma unroll
        for (int r = 0; r < 4; ++r) {
            int s = sbase + mt * 16 + quad * 4 + r;     // C/D: row = quad*4 + reg
            if (s < S) {
                out[(size_t)s * H_DIM + n0] = acc[mt][0][r] + b0;
                out[(size_t)s * H_DIM + n1] = acc[mt][1][r] + b1;
            }
        }
    }
}

// threads [0,E): ATOMIC-FREE placement p = off[slot] + blockbase[b][slot] + localrank.
// threads [E,E+S): snfo[s] = {off[canonical(s)], n} so seg's startup is ONE 8B load.
__global__ void place_kernel(const int* __restrict__ edge, const float* __restrict__ pos,
                             const float* __restrict__ normal,
                             const int* __restrict__ node2slot,
                             const unsigned short* __restrict__ rank16,
                             const int* __restrict__ off, const int* __restrict__ counts,
                             const int* __restrict__ nseg, const int* __restrict__ idx,
                             uint4* __restrict__ prec, int2* __restrict__ snfo,
                             int E, int S, int chunk) {
    int g = blockIdx.x * blockDim.x + threadIdx.x;
    if (g >= E) {
        int s = g - E;
        if (s < S) {
            int sp = node2slot[idx[s]];
            snfo[s] = make_int2(off[sp], nseg[sp]);
        }
        return;
    }
    int e0 = edge[g], e1 = edge[E + g];
    int slot = node2slot[e1];
    int b = g / chunk;
    int p = off[slot] + counts[(size_t)b * S + slot] + (int)rank16[g];
    float px = pos[3 * e0]     - pos[3 * e1];
    float py = pos[3 * e0 + 1] - pos[3 * e1 + 1];
    float pz = pos[3 * e0 + 2] - pos[3 * e1 + 2];
    float n0x = normal[3 * e0], n0y = normal[3 * e0 + 1], n0z = normal[3 * e0 + 2];
    float n1x = normal[3 * e1], n1y = normal[3 * e1 + 1], n1z = normal[3 * e1 + 2];
    float d  = sqrtf(px * px + py * py + pz * pz);
    float a1 = angle3(n1x, n1y, n1z, px, py, pz);
    float a2 = angle3(n0x, n0y, n0z, px, py, pz);
    float a3 = angle3(n1x, n1y, n1z, n0x, n0y, n0z);
    uint4 rec;
    rec.x = (unsigned)e0;
    rec.y = pk(d, a1);
    rec.z = pk(a2, a3);
    rec.w = 0;
    prec[p] = rec;
}

__device__ __forceinline__ void load_af(uint4 rec, const unsigned short* __restrict__ xbf,
                                        int quad, short8& a0, short8& a1, short8& a2) {
    const short8* xr = (const short8*)(xbf + (size_t)rec.x * F_DIM);
    a0 = xr[quad];          // k = quad*8 .. +8
    a1 = xr[4 + quad];      // k = 32 + quad*8 .. +8
    short8 z = (short8){0, 0, 0, 0, 0, 0, 0, 0};
    if (quad == 0) {        // k = 64..67 = ppf, 68..71 zero (wt2 rows 68+ are zero anyway)
        z[0] = (short)(rec.y & 0xffff); z[1] = (short)(rec.y >> 16);
        z[2] = (short)(rec.z & 0xffff); z[3] = (short)(rec.z >> 16);
    }
    a2 = z;
}

// wave-per-segment, STATIC interleaved assignment (R9: single-counter dynamic queue =
// serialized device atomics — never again). Segment startup = one int2 load (snfo).
// Dup slots recompute (same base/n as canonical). __launch_bounds__(256,2): the only
// clean regalloc regime (~88 VGPR needed; waves/EU=4 caps at 64 -> spills. R6+R8.)
__global__ __launch_bounds__(256, 2)
void seg_kernel(const unsigned short* __restrict__ xbf, const unsigned short* __restrict__ wt2,
                const uint4* __restrict__ prec, const int2* __restrict__ snfo,
                float* __restrict__ out, int S) {
    __shared__ __align__(16) unsigned short w_lds[H_DIM * LW2];
    {
        const uint4* src = (const uint4*)wt2;
        uint4* dst = (uint4*)w_lds;
        for (int g = threadIdx.x; g < H_DIM * LW2 / 8; g += 256) dst[g] = src[g];
    }
    __syncthreads();

    const int tid  = threadIdx.x;
    const int wv   = tid >> 6;
    const int lane = tid & 63;
    const int l15  = lane & 15;
    const int quad = lane >> 4;
    const int nw   = gridDim.x << 2;

    for (int s = (blockIdx.x << 2) + wv; s < S; s += nw) {
        const int2 nf = snfo[s];
        const int n = nf.y;
        float* orow = out + (size_t)s * H_DIM;
        if (n == 0) {                   // empty segment -> 0 (reference isfinite fixup)
            orow[lane] = 0.f;
            orow[64 + lane] = 0.f;
            continue;
        }
        const uint4* pb = prec + nf.x;

        float rm[8];
        #pragma unroll
        for (int ct = 0; ct < 8; ++ct) rm[ct] = -FLT_MAX;

        const int ntile = (n + 15) >> 4;
        int r = l15; if (r >= n) r = n - 1;   // pad rows = real edge dup -> exact for max
        uint4 rec = pb[r];
        short8 a0c, a1c, a2c;
        load_af(rec, xbf, quad, a0c, a1c, a2c);

        for (int t = 0; t < ntile; ++t) {
            // prefetch next tile's record + A-frags (overlaps the MFMAs below)
            uint4 recn = rec;
            if (t + 1 < ntile) {
                int rn = ((t + 1) << 4) + l15; if (rn >= n) rn = n - 1;
                recn = pb[rn];
            }
            short8 a0n, a1n, a2n;
            load_af(recn, xbf, quad, a0n, a1n, a2n);

            f32x4 acc[8];
            #pragma unroll
            for (int ct = 0; ct < 8; ++ct) acc[ct] = (f32x4){0.f, 0.f, 0.f, 0.f};
            #pragma unroll
            for (int ct = 0; ct < 8; ++ct) {
                const unsigned short* wc = w_lds + (ct * 16 + l15) * LW2 + (quad << 3);
                short8 b0 = *(const short8*)(wc);
                short8 b1 = *(const short8*)(wc + 32);
                short8 b2 = *(const short8*)(wc + 64);
                acc[ct] = __builtin_amdgcn_mfma_f32_16x16x32_bf16(a0c, b0, acc[ct], 0, 0, 0);
                acc[ct] = __builtin_amdgcn_mfma_f32_16x16x32_bf16(a1c, b1, acc[ct], 0, 0, 0);
                acc[ct] = __builtin_amdgcn_mfma_f32_16x16x32_bf16(a2c, b2, acc[ct], 0, 0, 0);
            }
            #pragma unroll
            for (int ct = 0; ct < 8; ++ct)
                rm[ct] = fmaxf(rm[ct], fmaxf(fmaxf(acc[ct][0], acc[ct][1]),
                                             fmaxf(acc[ct][2], acc[ct][3])));
            a0c = a0n; a1c = a1n; a2c = a2n; rec = recn;
        }

        #pragma unroll
        for (int ct = 0; ct < 8; ++ct) {
            rm[ct] = fmaxf(rm[ct], __shfl_xor(rm[ct], 16, 64));
            rm[ct] = fmaxf(rm[ct], __shfl_xor(rm[ct], 32, 64));
        }
        float v0 = rm[0], v1 = rm[4];   // col = ct*16 + l15; lane -> cols lane, lane+64
        if (quad == 1)      { v0 = rm[1]; v1 = rm[5]; }
        else if (quad == 2) { v0 = rm[2]; v1 = rm[6]; }
        else if (quad == 3) { v0 = rm[3]; v1 = rm[7]; }
        orow[lane]      = fmaxf(orow[lane] + v0, 0.f);    // c + max, relu (hoist exact)
        orow[64 + lane] = fmaxf(orow[64 + lane] + v1, 0.f);
    }
}

extern "C" void kernel_launch(void* const* d_in, const int* in_sizes, int n_in,
                              void* d_out, int out_size, void* d_ws, size_t ws_size,
                              hipStream_t stream) {
    const float* x      = (const float*)d_in[0];
    const float* pos    = (const float*)d_in[1];
    const float* normal = (const float*)d_in[2];
    const float* W      = (const float*)d_in[3];
    const float* b      = (const float*)d_in[4];
    const int*   edge   = (const int*)d_in[5];
    const int*   idx    = (const int*)d_in[6];

    const int H = in_sizes[4];            // 128
    const int K = in_sizes[3] / H;        // 132
    const int F = (K - 4) / 2;            // 64
    const int N = in_sizes[0] / F;        // 100000
    const int E = in_sizes[5] / 2;        // 800000
    const int S = in_sizes[6];            // 25000  (SMAX=25600 LDS histogram bound)

    // ws (256B aligned): wt2 | w1t | xbf[N*64]bf16 | prec[E]uint4 | node2slot[N]
    //                    | rank16[E] | counts[NB*S] | nseg[S] | off[S] | snfo[S] | total
    char* p = (char*)d_ws;
    auto alloc = [&](size_t bytes) { char* r = p; p += (bytes + 255) & ~(size_t)255; return r; };
    unsigned short* wt2 = (unsigned short*)alloc((size_t)H_DIM * LW2 * sizeof(unsigned short));
    unsigned short* w1t = (unsigned short*)alloc((size_t)H_DIM * LW1 * sizeof(unsigned short));
    unsigned short* xbf = (unsigned short*)alloc((size_t)N * F_DIM * sizeof(unsigned short));
    uint4* prec         = (uint4*)alloc((size_t)E * sizeof(uint4));
    int* node2slot      = (int*)alloc((size_t)N * sizeof(int));
    unsigned short* rank16 = (unsigned short*)alloc((size_t)E * sizeof(unsigned short));
    int* counts         = (int*)alloc((size_t)NB * S * sizeof(int));
    int* nseg           = (int*)alloc((size_t)S * sizeof(int));
    int* off            = (int*)alloc((size_t)S * sizeof(int));
    int2* snfo          = (int2*)alloc((size_t)S * sizeof(int2));
    int* total          = (int*)alloc(sizeof(int));
    float* out = (float*)d_out;           // cmat writes c, seg RMWs to final result

    const int AB = (S + 255) / 256;
    const int CB = (S + 63) / 64;
    const int NF8 = N * F_DIM / 8;
    const int chunk = (E + NB - 1) / NB;  // 6250 (< 65536: rank16 fits u16)

    hipMemsetAsync(total, 0, sizeof(int), stream);
    prep0<<<2048, 256, 0, stream>>>(W, wt2, w1t, x, xbf, idx, node2slot, pos, out, S, NF8);
    hist_kernel<<<NB, 1024, 0, stream>>>(edge, node2slot, rank16, counts, E, S, chunk);
    colscan<<<(S + 255) / 256, 256, 0, stream>>>(counts, nseg, S);
    alloc_cmat<<<AB + CB, 256, 0, stream>>>(nseg, off, total, xbf, w1t, b, idx, out, S, AB);
    place_kernel<<<(E + S + 255) / 256, 256, 0, stream>>>(edge, pos, normal, node2slot,
                                                          rank16, off, counts, nseg, idx,
                                                          prec, snfo, E, S, chunk);
    seg_kernel<<<2048, 256, 0, stream>>>(xbf, wt2, prec, snfo, out, S);
}

// Round 13
// 212.147 us; speedup vs baseline: 1.9014x; 1.0357x over previous
//
#include <hip/hip_runtime.h>
#include <hip/hip_bf16.h>
#include <float.h>

#define F_DIM 64
#define H_DIM 128
#define LW2   104   // wt2 row stride (bf16) for K=96 [x[e0]|ppf|pad]: 208 B, 16B-aligned
#define LW1   72    // w1t row stride (bf16) for K=64 [x[e1]]: 144 B, 16B-aligned
#define NB    128   // histogram blocks (counting-sort partitions)
#define SMAX  25600 // max slots supported by the LDS histogram (100 KB of 160 KB/CU)

typedef __attribute__((ext_vector_type(8))) short short8;   // 8 bf16 (mfma A/B frag)
typedef __attribute__((ext_vector_type(4))) float f32x4;    // mfma C/D frag

__device__ __forceinline__ unsigned short f2bf(float f) {
    __hip_bfloat16 h = __float2bfloat16(f);
    return __builtin_bit_cast(unsigned short, h);
}
__device__ __forceinline__ unsigned pk(float a, float b) {
    return (unsigned)f2bf(a) | ((unsigned)f2bf(b) << 16);
}

__device__ __forceinline__ float angle3(float ax, float ay, float az,
                                        float bx, float by, float bz) {
    float cx = ay*bz - az*by;
    float cy = az*bx - ax*bz;
    float cz = ax*by - ay*bx;
    float cn = sqrtf(cx*cx + cy*cy + cz*cz);
    float d  = ax*bx + ay*by + az*bz;
    return atan2f(cn, d);
}

// pure streaming pass, ZERO atomics (R11: 800K device atomics ≈ 40-50 µs floor —
// histogram lives in LDS now): wt2 + w1t builds, xbf (x->bf16 mfma layout),
// node2slot scatter, pos tail.
__global__ __launch_bounds__(256)
void prep0(const float* __restrict__ W, unsigned short* __restrict__ wt2,
           unsigned short* __restrict__ w1t, const float* __restrict__ x,
           unsigned short* __restrict__ xbf, const int* __restrict__ idx,
           int* __restrict__ node2slot, const float* __restrict__ pos,
           float* __restrict__ out, int S, int NF8) {
    const int T = gridDim.x * blockDim.x;
    const int gid = blockIdx.x * blockDim.x + threadIdx.x;
    for (int g = gid; g < NF8; g += T) {                  // x[N][64] f32 -> bf16, 8/thread
        const float4* s4 = (const float4*)x + (size_t)g * 2;
        float4 f0 = s4[0], f1 = s4[1];
        uint4 q;
        q.x = pk(f0.x, f0.y); q.y = pk(f0.z, f0.w);
        q.z = pk(f1.x, f1.y); q.w = pk(f1.z, f1.w);
        ((uint4*)xbf)[g] = q;
    }
    for (int g = gid; g < H_DIM * LW2; g += T) {          // W rows 64..131 -> [H][LW2]
        int h = g / LW2, k = g % LW2;
        float v = 0.f;
        if (k < F_DIM)          v = W[(F_DIM + k) * H_DIM + h];
        else if (k < F_DIM + 4) v = W[(2 * F_DIM + (k - F_DIM)) * H_DIM + h];
        wt2[g] = f2bf(v);
    }
    for (int g = gid; g < H_DIM * LW1; g += T) {          // W rows 0..63 -> [H][LW1]
        int h = g / LW1, k = g % LW1;
        w1t[g] = f2bf((k < F_DIM) ? W[k * H_DIM + h] : 0.f);
    }
    for (int g = gid; g < S; g += T) node2slot[idx[g]] = g;  // any winner = canonical slot
    for (int g = gid; g < 3 * S; g += T)                     // out tail = pos[idx]
        out[(size_t)S * H_DIM + g] = pos[(size_t)idx[g / 3] * 3 + (g % 3)];
}

// block-local LDS histogram (fast atomics, return = local rank), then dump counts row.
// Stable counting sort phase 1. Also zeroes the scan total (frees a memset dispatch).
__global__ __launch_bounds__(1024)
void hist_kernel(const int* __restrict__ edge, const int* __restrict__ node2slot,
                 unsigned short* __restrict__ rank16, int* __restrict__ counts,
                 int* __restrict__ total, int E, int S, int chunk) {
    __shared__ int hcnt[SMAX];
    if (blockIdx.x == 0 && threadIdx.x == 0) *total = 0;
    for (int i = threadIdx.x; i < S; i += 1024) hcnt[i] = 0;
    __syncthreads();
    const int base = blockIdx.x * chunk;
    int end = base + chunk; if (end > E) end = E;
    for (int e = base + (int)threadIdx.x; e < end; e += 1024) {
        int s = node2slot[edge[E + e]];     // every e1 is sampled -> canonical slot
        rank16[e] = (unsigned short)atomicAdd(&hcnt[s], 1);
    }
    __syncthreads();
    int* crow = counts + (size_t)blockIdx.x * S;
    for (int i = threadIdx.x; i < S; i += 1024) crow[i] = hcnt[i];
}

// blocks [0,AB): counting-sort phase 2 FUSED with slot-prefix: per-slot column scan
// across NB block rows (coalesced across threads) -> per-block bases + nseg, then
// wave/block scan over slots -> off. blocks [AB,AB+CB): cmat = b + x[idx]·W1 -> out
__global__ __launch_bounds__(256)
void alloc_cmat(int* __restrict__ counts, int* __restrict__ nseg,
                int* __restrict__ off, int* __restrict__ total,
                const unsigned short* __restrict__ xbf,
                const unsigned short* __restrict__ w1t, const float* __restrict__ bias,
                const int* __restrict__ idx, float* __restrict__ out, int S, int AB) {
    __shared__ int wsum[4];
    __shared__ int bb;
    __shared__ __align__(16) unsigned short a_lds[64 * LW1];
    const int tid = threadIdx.x;

    if ((int)blockIdx.x < AB) {
        int s = blockIdx.x * 256 + tid;
        int v = 0;
        if (s < S) {
            int acc = 0;
            for (int b2 = 0; b2 < NB; ++b2) {       // column scan (coalesced across tid)
                size_t o = (size_t)b2 * S + s;
                int c = counts[o];
                counts[o] = acc;
                acc += c;
            }
            nseg[s] = acc;                           // dup slots get 0 automatically
            v = acc;
        }
        int lane = tid & 63, wv = tid >> 6;
        int sc = v;
        #pragma unroll
        for (int d = 1; d < 64; d <<= 1) {
            int t = __shfl_up(sc, d, 64);
            if (lane >= d) sc += t;
        }
        if (lane == 63) wsum[wv] = sc;
        __syncthreads();
        if (tid == 0) {
            int t = 0;
            #pragma unroll
            for (int i = 0; i < 4; ++i) { int w = wsum[i]; wsum[i] = t; t += w; }
            bb = atomicAdd(total, t);
        }
        __syncthreads();
        int excl = bb + wsum[wv] + sc - v;
        if (s < S) off[s] = excl;
        return;
    }

    // ---- cmat: 64 slots per block, A rows from xbf (already bf16) ----
    const int sbase = (blockIdx.x - AB) * 64;
    const int m = tid >> 2, p = tid & 3;
    {
        int s = sbase + m; if (s >= S) s = S - 1;
        int node = idx[s];
        const uint4* src = (const uint4*)(xbf + (size_t)node * F_DIM) + p * 2;
        uint4* dst = (uint4*)(a_lds + m * LW1 + p * 16);
        dst[0] = src[0]; dst[1] = src[1];
        if (p == 0) *(uint4*)(a_lds + m * LW1 + 64) = make_uint4(0, 0, 0, 0);
    }
    __syncthreads();
    const int wv = tid >> 6, lane = tid & 63, l15 = lane & 15, quad = lane >> 4;
    const int n0 = wv * 32 + l15, n1 = n0 + 16;
    f32x4 acc[4][2];
    #pragma unroll
    for (int i = 0; i < 4; ++i) {
        acc[i][0] = (f32x4){0.f, 0.f, 0.f, 0.f};
        acc[i][1] = (f32x4){0.f, 0.f, 0.f, 0.f};
    }
    #pragma unroll
    for (int ks = 0; ks < 2; ++ks) {
        const int ko = ks * 32 + quad * 8;
        short8 bf0 = *(const short8*)(w1t + (size_t)n0 * LW1 + ko);
        short8 bf1 = *(const short8*)(w1t + (size_t)n1 * LW1 + ko);
        #pragma unroll
        for (int mt = 0; mt < 4; ++mt) {
            short8 af = *(const short8*)(a_lds + (mt * 16 + l15) * LW1 + ko);
            acc[mt][0] = __builtin_amdgcn_mfma_f32_16x16x32_bf16(af, bf0, acc[mt][0], 0, 0, 0);
            acc[mt][1] = __builtin_amdgcn_mfma_f32_16x16x32_bf16(af, bf1, acc[mt][1], 0, 0, 0);
        }
    }
    const float b0 = bias[n0], b1 = bias[n1];
    #pragma unroll
    for (int mt = 0; mt < 4; ++mt) {
        #pragma unroll
        for (int r = 0; r < 4; ++r) {
            int s = sbase + mt * 16 + quad * 4 + r;     // C/D: row = quad*4 + reg
            if (s < S) {
                out[(size_t)s * H_DIM + n0] = acc[mt][0][r] + b0;
                out[(size_t)s * H_DIM + n1] = acc[mt][1][r] + b1;
            }
        }
    }
}

// threads [0,E): ATOMIC-FREE placement p = off[slot] + blockbase[b][slot] + localrank.
// threads [E,E+S): snfo[s] = {off[canonical(s)], n} so seg's startup is ONE 8B load.
__global__ void place_kernel(const int* __restrict__ edge, const float* __restrict__ pos,
                             const float* __restrict__ normal,
                             const int* __restrict__ node2slot,
                             const unsigned short* __restrict__ rank16,
                             const int* __restrict__ off, const int* __restrict__ counts,
                             const int* __restrict__ nseg, const int* __restrict__ idx,
                             uint4* __restrict__ prec, int2* __restrict__ snfo,
                             int E, int S, int chunk) {
    int g = blockIdx.x * blockDim.x + threadIdx.x;
    if (g >= E) {
        int s = g - E;
        if (s < S) {
            int sp = node2slot[idx[s]];
            snfo[s] = make_int2(off[sp], nseg[sp]);
        }
        return;
    }
    int e0 = edge[g], e1 = edge[E + g];
    int slot = node2slot[e1];
    int b = g / chunk;
    int p = off[slot] + counts[(size_t)b * S + slot] + (int)rank16[g];
    float px = pos[3 * e0]     - pos[3 * e1];
    float py = pos[3 * e0 + 1] - pos[3 * e1 + 1];
    float pz = pos[3 * e0 + 2] - pos[3 * e1 + 2];
    float n0x = normal[3 * e0], n0y = normal[3 * e0 + 1], n0z = normal[3 * e0 + 2];
    float n1x = normal[3 * e1], n1y = normal[3 * e1 + 1], n1z = normal[3 * e1 + 2];
    float d  = sqrtf(px * px + py * py + pz * pz);
    float a1 = angle3(n1x, n1y, n1z, px, py, pz);
    float a2 = angle3(n0x, n0y, n0z, px, py, pz);
    float a3 = angle3(n1x, n1y, n1z, n0x, n0y, n0z);
    uint4 rec;
    rec.x = (unsigned)e0;
    rec.y = pk(d, a1);
    rec.z = pk(a2, a3);
    rec.w = 0;
    prec[p] = rec;
}

__device__ __forceinline__ void load_af(uint4 rec, const unsigned short* __restrict__ xbf,
                                        int quad, short8& a0, short8& a1, short8& a2) {
    const short8* xr = (const short8*)(xbf + (size_t)rec.x * F_DIM);
    a0 = xr[quad];          // k = quad*8 .. +8
    a1 = xr[4 + quad];      // k = 32 + quad*8 .. +8
    short8 z = (short8){0, 0, 0, 0, 0, 0, 0, 0};
    if (quad == 0) {        // k = 64..67 = ppf, 68..71 zero (wt2 rows 68+ are zero anyway)
        z[0] = (short)(rec.y & 0xffff); z[1] = (short)(rec.y >> 16);
        z[2] = (short)(rec.z & 0xffff); z[3] = (short)(rec.z >> 16);
    }
    a2 = z;
}

// wave-per-segment, STATIC interleave (R9: central dynamic queue = serialized device
// atomics — never). Startup = one int2 (snfo). DEPTH-2 record prefetch: records are
// fetched two tiles ahead so each tile's A-gather issues against an already-resident
// record — breaks the 2-hop (rec -> xbf) L2-latency chain that capped R12 at 57 µs.
// __launch_bounds__(256,2): the only clean regalloc regime (R6+R8: waves/EU=4 -> spill).
__global__ __launch_bounds__(256, 2)
void seg_kernel(const unsigned short* __restrict__ xbf, const unsigned short* __restrict__ wt2,
                const uint4* __restrict__ prec, const int2* __restrict__ snfo,
                float* __restrict__ out, int S) {
    __shared__ __align__(16) unsigned short w_lds[H_DIM * LW2];
    {
        const uint4* src = (const uint4*)wt2;
        uint4* dst = (uint4*)w_lds;
        for (int g = threadIdx.x; g < H_DIM * LW2 / 8; g += 256) dst[g] = src[g];
    }
    __syncthreads();

    const int tid  = threadIdx.x;
    const int wv   = tid >> 6;
    const int lane = tid & 63;
    const int l15  = lane & 15;
    const int quad = lane >> 4;
    const int nw   = gridDim.x << 2;

    for (int s = (blockIdx.x << 2) + wv; s < S; s += nw) {
        const int2 nf = snfo[s];
        const int n = nf.y;
        float* orow = out + (size_t)s * H_DIM;
        if (n == 0) {                   // empty segment -> 0 (reference isfinite fixup)
            orow[lane] = 0.f;
            orow[64 + lane] = 0.f;
            continue;
        }
        const uint4* pb = prec + nf.x;

        float rm[8];
        #pragma unroll
        for (int ct = 0; ct < 8; ++ct) rm[ct] = -FLT_MAX;

        const int ntile = (n + 15) >> 4;
        int r0 = l15;      if (r0 >= n) r0 = n - 1;   // pad rows = real dup -> exact for max
        int r1 = 16 + l15; if (r1 >= n) r1 = n - 1;
        uint4 rec_c = pb[r0];
        uint4 rec_n = (ntile > 1) ? pb[r1] : rec_c;
        short8 a0c, a1c, a2c;
        load_af(rec_c, xbf, quad, a0c, a1c, a2c);

        for (int t = 0; t < ntile; ++t) {
            // rec two tiles ahead; A-frags one tile ahead from an already-resident rec
            uint4 rec_nn = rec_n;
            if (t + 2 < ntile) {
                int rn = ((t + 2) << 4) + l15; if (rn >= n) rn = n - 1;
                rec_nn = pb[rn];
            }
            short8 a0n, a1n, a2n;
            load_af(rec_n, xbf, quad, a0n, a1n, a2n);

            f32x4 acc[8];
            #pragma unroll
            for (int ct = 0; ct < 8; ++ct) acc[ct] = (f32x4){0.f, 0.f, 0.f, 0.f};
            #pragma unroll
            for (int ct = 0; ct < 8; ++ct) {
                const unsigned short* wc = w_lds + (ct * 16 + l15) * LW2 + (quad << 3);
                short8 b0 = *(const short8*)(wc);
                short8 b1 = *(const short8*)(wc + 32);
                short8 b2 = *(const short8*)(wc + 64);
                acc[ct] = __builtin_amdgcn_mfma_f32_16x16x32_bf16(a0c, b0, acc[ct], 0, 0, 0);
                acc[ct] = __builtin_amdgcn_mfma_f32_16x16x32_bf16(a1c, b1, acc[ct], 0, 0, 0);
                acc[ct] = __builtin_amdgcn_mfma_f32_16x16x32_bf16(a2c, b2, acc[ct], 0, 0, 0);
            }
            #pragma unroll
            for (int ct = 0; ct < 8; ++ct)
                rm[ct] = fmaxf(rm[ct], fmaxf(fmaxf(acc[ct][0], acc[ct][1]),
                                             fmaxf(acc[ct][2], acc[ct][3])));
            a0c = a0n; a1c = a1n; a2c = a2n;
            rec_n = rec_nn;
        }

        #pragma unroll
        for (int ct = 0; ct < 8; ++ct) {
            rm[ct] = fmaxf(rm[ct], __shfl_xor(rm[ct], 16, 64));
            rm[ct] = fmaxf(rm[ct], __shfl_xor(rm[ct], 32, 64));
        }
        float v0 = rm[0], v1 = rm[4];   // col = ct*16 + l15; lane -> cols lane, lane+64
        if (quad == 1)      { v0 = rm[1]; v1 = rm[5]; }
        else if (quad == 2) { v0 = rm[2]; v1 = rm[6]; }
        else if (quad == 3) { v0 = rm[3]; v1 = rm[7]; }
        orow[lane]      = fmaxf(orow[lane] + v0, 0.f);    // c + max, relu (hoist exact)
        orow[64 + lane] = fmaxf(orow[64 + lane] + v1, 0.f);
    }
}

extern "C" void kernel_launch(void* const* d_in, const int* in_sizes, int n_in,
                              void* d_out, int out_size, void* d_ws, size_t ws_size,
                              hipStream_t stream) {
    const float* x      = (const float*)d_in[0];
    const float* pos    = (const float*)d_in[1];
    const float* normal = (const float*)d_in[2];
    const float* W      = (const float*)d_in[3];
    const float* b      = (const float*)d_in[4];
    const int*   edge   = (const int*)d_in[5];
    const int*   idx    = (const int*)d_in[6];

    const int H = in_sizes[4];            // 128
    const int K = in_sizes[3] / H;        // 132
    const int F = (K - 4) / 2;            // 64
    const int N = in_sizes[0] / F;        // 100000
    const int E = in_sizes[5] / 2;        // 800000
    const int S = in_sizes[6];            // 25000  (SMAX=25600 LDS histogram bound)

    // ws (256B aligned): wt2 | w1t | xbf[N*64]bf16 | prec[E]uint4 | node2slot[N]
    //                    | rank16[E] | counts[NB*S] | nseg[S] | off[S] | snfo[S] | total
    char* p = (char*)d_ws;
    auto alloc = [&](size_t bytes) { char* r = p; p += (bytes + 255) & ~(size_t)255; return r; };
    unsigned short* wt2 = (unsigned short*)alloc((size_t)H_DIM * LW2 * sizeof(unsigned short));
    unsigned short* w1t = (unsigned short*)alloc((size_t)H_DIM * LW1 * sizeof(unsigned short));
    unsigned short* xbf = (unsigned short*)alloc((size_t)N * F_DIM * sizeof(unsigned short));
    uint4* prec         = (uint4*)alloc((size_t)E * sizeof(uint4));
    int* node2slot      = (int*)alloc((size_t)N * sizeof(int));
    unsigned short* rank16 = (unsigned short*)alloc((size_t)E * sizeof(unsigned short));
    int* counts         = (int*)alloc((size_t)NB * S * sizeof(int));
    int* nseg           = (int*)alloc((size_t)S * sizeof(int));
    int* off            = (int*)alloc((size_t)S * sizeof(int));
    int2* snfo          = (int2*)alloc((size_t)S * sizeof(int2));
    int* total          = (int*)alloc(sizeof(int));
    float* out = (float*)d_out;           // cmat writes c, seg RMWs to final result

    const int AB = (S + 255) / 256;
    const int CB = (S + 63) / 64;
    const int NF8 = N * F_DIM / 8;
    const int chunk = (E + NB - 1) / NB;  // 6250 (< 65536: rank16 fits u16)

    prep0<<<2048, 256, 0, stream>>>(W, wt2, w1t, x, xbf, idx, node2slot, pos, out, S, NF8);
    hist_kernel<<<NB, 1024, 0, stream>>>(edge, node2slot, rank16, counts, total, E, S, chunk);
    alloc_cmat<<<AB + CB, 256, 0, stream>>>(counts, nseg, off, total, xbf, w1t, b,
                                            idx, out, S, AB);
    place_kernel<<<(E + S + 255) / 256, 256, 0, stream>>>(edge, pos, normal, node2slot,
                                                          rank16, off, counts, nseg, idx,
                                                          prec, snfo, E, S, chunk);
    seg_kernel<<<2048, 256, 0, stream>>>(xbf, wt2, prec, snfo, out, S);
}